// Round 1
// baseline (479.733 us; speedup 1.0000x reference)
//
#include <hip/hip_runtime.h>
#include <math.h>

#define TPB 256
#define CCLS 1000   // classes; 250 threads x float4

// ---------------- main kernel: per-row L2-normalized softmax, accumulate per-class sums ----------------
__global__ __launch_bounds__(TPB) void mdca_main(
    const float* __restrict__ X, float* __restrict__ g_acc, int B) {
  __shared__ float sacc[4 * TPB];          // class accumulator, layout [j][t] -> conflict-free
  __shared__ float s_s[4], s_m[4], s_e[4]; // cross-wave reduce scratch (4 waves)
  const int t = threadIdx.x;
  const int lane = t & 63;
  const int wave = t >> 6;
  const bool act = (t < CCLS / 4);         // t < 250

  #pragma unroll
  for (int j = 0; j < 4; ++j) sacc[j * TPB + t] = 0.0f;
  __syncthreads();

  for (int row = blockIdx.x; row < B; row += gridDim.x) {
    float4 x;
    if (act) x = *reinterpret_cast<const float4*>(X + (size_t)row * CCLS + t * 4);
    else     x = make_float4(0.f, 0.f, 0.f, 0.f);

    // fused block-reduce: sum of squares + max (max(x*inv) == max(x)*inv, inv > 0)
    float ss = x.x * x.x + x.y * x.y + x.z * x.z + x.w * x.w;
    float mx = act ? fmaxf(fmaxf(x.x, x.y), fmaxf(x.z, x.w)) : -INFINITY;
    #pragma unroll
    for (int off = 32; off > 0; off >>= 1) {
      ss += __shfl_down(ss, off, 64);
      mx = fmaxf(mx, __shfl_down(mx, off, 64));
    }
    if (lane == 0) { s_s[wave] = ss; s_m[wave] = mx; }
    __syncthreads();
    float tot_ss = s_s[0] + s_s[1] + s_s[2] + s_s[3];
    float tot_mx = fmaxf(fmaxf(s_m[0], s_m[1]), fmaxf(s_m[2], s_m[3]));
    float inv = 1.0f / (sqrtf(tot_ss) + 1e-7f);
    float M = tot_mx * inv;

    float e0 = 0.f, e1 = 0.f, e2 = 0.f, e3 = 0.f;
    if (act) {
      e0 = __expf(x.x * inv - M);
      e1 = __expf(x.y * inv - M);
      e2 = __expf(x.z * inv - M);
      e3 = __expf(x.w * inv - M);
    }
    float es = e0 + e1 + e2 + e3;
    #pragma unroll
    for (int off = 32; off > 0; off >>= 1) es += __shfl_down(es, off, 64);
    if (lane == 0) s_e[wave] = es;
    __syncthreads();
    float invS = 1.0f / (s_e[0] + s_e[1] + s_e[2] + s_e[3]);

    if (act) {
      sacc[0 * TPB + t] += e0 * invS;
      sacc[1 * TPB + t] += e1 * invS;
      sacc[2 * TPB + t] += e2 * invS;
      sacc[3 * TPB + t] += e3 * invS;
    }
    __syncthreads();  // protect s_s/s_m/s_e for next row
  }

  if (act) {
    #pragma unroll
    for (int j = 0; j < 4; ++j)
      atomicAdd(&g_acc[t * 4 + j], sacc[j * TPB + t]);
  }
}

// ---------------- bincount of targets ----------------
__global__ __launch_bounds__(TPB) void mdca_count(
    const int* __restrict__ tgt, float* __restrict__ g_cnt, int B) {
  int i = blockIdx.x * blockDim.x + threadIdx.x;
  if (i < B) atomicAdd(&g_cnt[tgt[i]], 1.0f);
}

// ---------------- epilogue: mean |avg_conf - avg_count| ----------------
__global__ __launch_bounds__(TPB) void mdca_final(
    const float* __restrict__ g_acc, const float* __restrict__ g_cnt,
    float* __restrict__ out, int B) {
  __shared__ float s_r[4];
  int t = threadIdx.x;
  float invB = 1.0f / (float)B;
  float s = 0.f;
  for (int c = t; c < CCLS; c += TPB)
    s += fabsf((g_acc[c] - g_cnt[c]) * invB);
  #pragma unroll
  for (int off = 32; off > 0; off >>= 1) s += __shfl_down(s, off, 64);
  if ((t & 63) == 0) s_r[t >> 6] = s;
  __syncthreads();
  if (t == 0) out[0] = (s_r[0] + s_r[1] + s_r[2] + s_r[3]) / (float)CCLS;
}

extern "C" void kernel_launch(void* const* d_in, const int* in_sizes, int n_in,
                              void* d_out, int out_size, void* d_ws, size_t ws_size,
                              hipStream_t stream) {
  const float* X  = (const float*)d_in[0];
  const int* tgt  = (const int*)d_in[1];
  const int B = in_sizes[1];

  float* g_acc = (float*)d_ws;          // [1024] (first 1000 used)
  float* g_cnt = g_acc + 1024;          // [1024]

  hipMemsetAsync(d_ws, 0, 2048 * sizeof(float), stream);

  mdca_main<<<1024, TPB, 0, stream>>>(X, g_acc, B);
  mdca_count<<<(B + TPB - 1) / TPB, TPB, 0, stream>>>(tgt, g_cnt, B);
  mdca_final<<<1, TPB, 0, stream>>>(g_acc, g_cnt, (float*)d_out, B);
}

// Round 2
// 421.595 us; speedup vs baseline: 1.1379x; 1.1379x over previous
//
#include <hip/hip_runtime.h>
#include <math.h>

#define TPB 256
#define NBLK 1024
#define CCLS 1000

// One row per wave: lane l owns float4 chunks {l, 64+l, 128+l, 192+l} (last valid if l<58).
// Class index of chunk k, lane l, component j:  c = k*256 + l*4 + j  (0..1023, <1000 valid).
__global__ __launch_bounds__(TPB) void mdca_main(const float* __restrict__ X,
                                                 float* __restrict__ g_acc, int B) {
  __shared__ float sacc[1024];
  const int t = threadIdx.x;
  const int lane = t & 63;
  const int wid = blockIdx.x * (TPB / 64) + (t >> 6);
  const int nw = gridDim.x * (TPB / 64);
  const bool v3 = (lane < 58);  // chunk 192+lane < 250

  for (int i = t; i < 1024; i += TPB) sacc[i] = 0.f;

  float acc[16];
  #pragma unroll
  for (int i = 0; i < 16; ++i) acc[i] = 0.f;

  const float4 Z = make_float4(0.f, 0.f, 0.f, 0.f);

  for (int r0 = wid; r0 < B; r0 += 2 * nw) {
    const int r1 = r0 + nw;
    const bool has1 = (r1 < B);

    const float4* b0 = reinterpret_cast<const float4*>(X + (size_t)r0 * CCLS);
    const float4* b1 = reinterpret_cast<const float4*>(X + (size_t)(has1 ? r1 : r0) * CCLS);

    // issue all loads for both rows up front
    float4 a0 = b0[lane],      a1 = b0[64 + lane];
    float4 a2 = b0[128 + lane], a3 = v3 ? b0[192 + lane] : Z;
    float4 c0 = b1[lane],      c1 = b1[64 + lane];
    float4 c2 = b1[128 + lane], c3 = v3 ? b1[192 + lane] : Z;

    // sum-of-squares + max, both rows
    float ss0 = a0.x*a0.x + a0.y*a0.y + a0.z*a0.z + a0.w*a0.w
              + a1.x*a1.x + a1.y*a1.y + a1.z*a1.z + a1.w*a1.w
              + a2.x*a2.x + a2.y*a2.y + a2.z*a2.z + a2.w*a2.w
              + a3.x*a3.x + a3.y*a3.y + a3.z*a3.z + a3.w*a3.w;
    float mx0 = fmaxf(fmaxf(fmaxf(a0.x, a0.y), fmaxf(a0.z, a0.w)),
                fmaxf(fmaxf(fmaxf(a1.x, a1.y), fmaxf(a1.z, a1.w)),
                      fmaxf(fmaxf(a2.x, a2.y), fmaxf(a2.z, a2.w))));
    if (v3) mx0 = fmaxf(mx0, fmaxf(fmaxf(a3.x, a3.y), fmaxf(a3.z, a3.w)));

    float ss1 = c0.x*c0.x + c0.y*c0.y + c0.z*c0.z + c0.w*c0.w
              + c1.x*c1.x + c1.y*c1.y + c1.z*c1.z + c1.w*c1.w
              + c2.x*c2.x + c2.y*c2.y + c2.z*c2.z + c2.w*c2.w
              + c3.x*c3.x + c3.y*c3.y + c3.z*c3.z + c3.w*c3.w;
    float mx1 = fmaxf(fmaxf(fmaxf(c0.x, c0.y), fmaxf(c0.z, c0.w)),
                fmaxf(fmaxf(fmaxf(c1.x, c1.y), fmaxf(c1.z, c1.w)),
                      fmaxf(fmaxf(c2.x, c2.y), fmaxf(c2.z, c2.w))));
    if (v3) mx1 = fmaxf(mx1, fmaxf(fmaxf(c3.x, c3.y), fmaxf(c3.z, c3.w)));

    // wave butterfly reduce (no barriers, all lanes get result)
    #pragma unroll
    for (int off = 1; off < 64; off <<= 1) {
      ss0 += __shfl_xor(ss0, off, 64);
      mx0 = fmaxf(mx0, __shfl_xor(mx0, off, 64));
      ss1 += __shfl_xor(ss1, off, 64);
      mx1 = fmaxf(mx1, __shfl_xor(mx1, off, 64));
    }

    const float inv0 = 1.0f / (sqrtf(ss0) + 1e-7f);
    const float inv1 = 1.0f / (sqrtf(ss1) + 1e-7f);
    const float M0 = mx0 * inv0;
    const float M1 = mx1 * inv1;

    float e0[16], e1[16];
    e0[0]=__expf(a0.x*inv0-M0); e0[1]=__expf(a0.y*inv0-M0); e0[2]=__expf(a0.z*inv0-M0); e0[3]=__expf(a0.w*inv0-M0);
    e0[4]=__expf(a1.x*inv0-M0); e0[5]=__expf(a1.y*inv0-M0); e0[6]=__expf(a1.z*inv0-M0); e0[7]=__expf(a1.w*inv0-M0);
    e0[8]=__expf(a2.x*inv0-M0); e0[9]=__expf(a2.y*inv0-M0); e0[10]=__expf(a2.z*inv0-M0); e0[11]=__expf(a2.w*inv0-M0);
    e1[0]=__expf(c0.x*inv1-M1); e1[1]=__expf(c0.y*inv1-M1); e1[2]=__expf(c0.z*inv1-M1); e1[3]=__expf(c0.w*inv1-M1);
    e1[4]=__expf(c1.x*inv1-M1); e1[5]=__expf(c1.y*inv1-M1); e1[6]=__expf(c1.z*inv1-M1); e1[7]=__expf(c1.w*inv1-M1);
    e1[8]=__expf(c2.x*inv1-M1); e1[9]=__expf(c2.y*inv1-M1); e1[10]=__expf(c2.z*inv1-M1); e1[11]=__expf(c2.w*inv1-M1);
    if (v3) {
      e0[12]=__expf(a3.x*inv0-M0); e0[13]=__expf(a3.y*inv0-M0); e0[14]=__expf(a3.z*inv0-M0); e0[15]=__expf(a3.w*inv0-M0);
      e1[12]=__expf(c3.x*inv1-M1); e1[13]=__expf(c3.y*inv1-M1); e1[14]=__expf(c3.z*inv1-M1); e1[15]=__expf(c3.w*inv1-M1);
    } else {
      e0[12]=e0[13]=e0[14]=e0[15]=0.f;
      e1[12]=e1[13]=e1[14]=e1[15]=0.f;
    }

    float es0 = 0.f, es1 = 0.f;
    #pragma unroll
    for (int i = 0; i < 16; ++i) { es0 += e0[i]; es1 += e1[i]; }
    #pragma unroll
    for (int off = 1; off < 64; off <<= 1) {
      es0 += __shfl_xor(es0, off, 64);
      es1 += __shfl_xor(es1, off, 64);
    }
    const float invS0 = 1.0f / es0;
    const float invS1 = has1 ? (1.0f / es1) : 0.f;  // mask row1 if out of range

    #pragma unroll
    for (int i = 0; i < 16; ++i) acc[i] += e0[i] * invS0 + e1[i] * invS1;
  }

  // combine 4 waves in LDS (sacc index == class index), then one atomic/class/block
  __syncthreads();  // sacc zeroed by all threads above
  #pragma unroll
  for (int k = 0; k < 4; ++k)
    #pragma unroll
    for (int j = 0; j < 4; ++j)
      atomicAdd(&sacc[k * 256 + lane * 4 + j], acc[k * 4 + j]);
  __syncthreads();
  #pragma unroll
  for (int j = 0; j < 4; ++j) {
    int c = t * 4 + j;
    if (c < CCLS) atomicAdd(&g_acc[c], sacc[c]);
  }
}

// ---------------- bincount via LDS histogram ----------------
__global__ __launch_bounds__(TPB) void mdca_count(const int* __restrict__ tgt,
                                                  float* __restrict__ g_cnt, int B) {
  __shared__ int scnt[CCLS];
  for (int i = threadIdx.x; i < CCLS; i += TPB) scnt[i] = 0;
  __syncthreads();
  for (int i = blockIdx.x * TPB + threadIdx.x; i < B; i += gridDim.x * TPB)
    atomicAdd(&scnt[tgt[i]], 1);
  __syncthreads();
  for (int i = threadIdx.x; i < CCLS; i += TPB) {
    int v = scnt[i];
    if (v) atomicAdd(&g_cnt[i], (float)v);
  }
}

// ---------------- epilogue: mean |avg_conf - avg_count| ----------------
__global__ __launch_bounds__(TPB) void mdca_final(const float* __restrict__ g_acc,
                                                  const float* __restrict__ g_cnt,
                                                  float* __restrict__ out, int B) {
  __shared__ float s_r[4];
  int t = threadIdx.x;
  float invB = 1.0f / (float)B;
  float s = 0.f;
  for (int c = t; c < CCLS; c += TPB)
    s += fabsf((g_acc[c] - g_cnt[c]) * invB);
  #pragma unroll
  for (int off = 32; off > 0; off >>= 1) s += __shfl_down(s, off, 64);
  if ((t & 63) == 0) s_r[t >> 6] = s;
  __syncthreads();
  if (t == 0) out[0] = (s_r[0] + s_r[1] + s_r[2] + s_r[3]) / (float)CCLS;
}

extern "C" void kernel_launch(void* const* d_in, const int* in_sizes, int n_in,
                              void* d_out, int out_size, void* d_ws, size_t ws_size,
                              hipStream_t stream) {
  const float* X = (const float*)d_in[0];
  const int* tgt = (const int*)d_in[1];
  const int B = in_sizes[1];

  float* g_acc = (float*)d_ws;   // [1024] (first 1000 used)
  float* g_cnt = g_acc + 1024;   // [1024]

  hipMemsetAsync(d_ws, 0, 2048 * sizeof(float), stream);

  mdca_main<<<NBLK, TPB, 0, stream>>>(X, g_acc, B);
  mdca_count<<<32, TPB, 0, stream>>>(tgt, g_cnt, B);
  mdca_final<<<1, TPB, 0, stream>>>(g_acc, g_cnt, (float*)d_out, B);
}

// Round 3
// 406.924 us; speedup vs baseline: 1.1789x; 1.0361x over previous
//
#include <hip/hip_runtime.h>
#include <math.h>

#define TPB 512          // 8 waves/block; 1024 blocks -> 8 waves/SIMD (full occupancy)
#define NBLK 1024
#define CCLS 1000

// One row per wave: lane l owns float4 chunks {l, 64+l, 128+l, 192+l} (last valid if l<58).
// Class index of chunk k, lane l, component j:  c = k*256 + l*4 + j  (0..1023, <1000 valid).
// NOTE: no max-subtraction needed — x*inv in [-1,1] after L2 norm, exp in [0.37, 2.72],
// and softmax is shift-invariant, so result is identical.
__global__ __launch_bounds__(TPB, 8) void mdca_main(const float* __restrict__ X,
                                                    float* __restrict__ g_acc, int B) {
  __shared__ float sacc[1024];
  const int t = threadIdx.x;
  const int lane = t & 63;
  const int wid = blockIdx.x * (TPB / 64) + (t >> 6);
  const int nw = NBLK * (TPB / 64);   // 8192 waves
  const bool v3 = (lane < 58);        // chunk 192+lane < 250

  for (int i = t; i < 1024; i += TPB) sacc[i] = 0.f;

  float acc[16];
  #pragma unroll
  for (int i = 0; i < 16; ++i) acc[i] = 0.f;

  const float4 Z = make_float4(0.f, 0.f, 0.f, 0.f);

  for (int r0 = wid; r0 < B; r0 += 2 * nw) {
    const int r1 = r0 + nw;
    const bool has1 = (r1 < B);

    const float4* b0 = reinterpret_cast<const float4*>(X + (size_t)r0 * CCLS);
    const float4* b1 = reinterpret_cast<const float4*>(X + (size_t)(has1 ? r1 : r0) * CCLS);

    // issue all loads for both rows up front
    float4 a0 = b0[lane],       a1 = b0[64 + lane];
    float4 a2 = b0[128 + lane], a3 = v3 ? b0[192 + lane] : Z;
    float4 c0 = b1[lane],       c1 = b1[64 + lane];
    float4 c2 = b1[128 + lane], c3 = v3 ? b1[192 + lane] : Z;

    // sum of squares (no max needed)
    float ss0 = a0.x*a0.x + a0.y*a0.y + a0.z*a0.z + a0.w*a0.w
              + a1.x*a1.x + a1.y*a1.y + a1.z*a1.z + a1.w*a1.w
              + a2.x*a2.x + a2.y*a2.y + a2.z*a2.z + a2.w*a2.w
              + a3.x*a3.x + a3.y*a3.y + a3.z*a3.z + a3.w*a3.w;
    float ss1 = c0.x*c0.x + c0.y*c0.y + c0.z*c0.z + c0.w*c0.w
              + c1.x*c1.x + c1.y*c1.y + c1.z*c1.z + c1.w*c1.w
              + c2.x*c2.x + c2.y*c2.y + c2.z*c2.z + c2.w*c2.w
              + c3.x*c3.x + c3.y*c3.y + c3.z*c3.z + c3.w*c3.w;

    #pragma unroll
    for (int off = 1; off < 64; off <<= 1) {
      ss0 += __shfl_xor(ss0, off, 64);
      ss1 += __shfl_xor(ss1, off, 64);
    }

    const float inv0 = 1.0f / (sqrtf(ss0) + 1e-7f);
    const float inv1 = 1.0f / (sqrtf(ss1) + 1e-7f);

    float e0[16], e1[16];
    e0[0]=__expf(a0.x*inv0); e0[1]=__expf(a0.y*inv0); e0[2]=__expf(a0.z*inv0); e0[3]=__expf(a0.w*inv0);
    e0[4]=__expf(a1.x*inv0); e0[5]=__expf(a1.y*inv0); e0[6]=__expf(a1.z*inv0); e0[7]=__expf(a1.w*inv0);
    e0[8]=__expf(a2.x*inv0); e0[9]=__expf(a2.y*inv0); e0[10]=__expf(a2.z*inv0); e0[11]=__expf(a2.w*inv0);
    e1[0]=__expf(c0.x*inv1); e1[1]=__expf(c0.y*inv1); e1[2]=__expf(c0.z*inv1); e1[3]=__expf(c0.w*inv1);
    e1[4]=__expf(c1.x*inv1); e1[5]=__expf(c1.y*inv1); e1[6]=__expf(c1.z*inv1); e1[7]=__expf(c1.w*inv1);
    e1[8]=__expf(c2.x*inv1); e1[9]=__expf(c2.y*inv1); e1[10]=__expf(c2.z*inv1); e1[11]=__expf(c2.w*inv1);
    if (v3) {
      e0[12]=__expf(a3.x*inv0); e0[13]=__expf(a3.y*inv0); e0[14]=__expf(a3.z*inv0); e0[15]=__expf(a3.w*inv0);
      e1[12]=__expf(c3.x*inv1); e1[13]=__expf(c3.y*inv1); e1[14]=__expf(c3.z*inv1); e1[15]=__expf(c3.w*inv1);
    } else {
      e0[12]=e0[13]=e0[14]=e0[15]=0.f;
      e1[12]=e1[13]=e1[14]=e1[15]=0.f;
    }

    float es0 = 0.f, es1 = 0.f;
    #pragma unroll
    for (int i = 0; i < 16; ++i) { es0 += e0[i]; es1 += e1[i]; }
    #pragma unroll
    for (int off = 1; off < 64; off <<= 1) {
      es0 += __shfl_xor(es0, off, 64);
      es1 += __shfl_xor(es1, off, 64);
    }
    const float invS0 = 1.0f / es0;
    const float invS1 = has1 ? (1.0f / es1) : 0.f;   // mask row1 if out of range

    #pragma unroll
    for (int i = 0; i < 16; ++i) acc[i] += e0[i] * invS0 + e1[i] * invS1;
  }

  // combine 8 waves in LDS (sacc index == class index), then one atomic/class/block
  __syncthreads();   // sacc zeroed above
  #pragma unroll
  for (int k = 0; k < 4; ++k)
    #pragma unroll
    for (int j = 0; j < 4; ++j)
      atomicAdd(&sacc[k * 256 + lane * 4 + j], acc[k * 4 + j]);
  __syncthreads();
  #pragma unroll
  for (int j = 0; j < 2; ++j) {
    int c = t * 2 + j;
    if (c < CCLS) atomicAdd(&g_acc[c], sacc[c]);
  }
}

// ---------------- bincount via LDS histogram ----------------
__global__ __launch_bounds__(256) void mdca_count(const int* __restrict__ tgt,
                                                  float* __restrict__ g_cnt, int B) {
  __shared__ int scnt[CCLS];
  for (int i = threadIdx.x; i < CCLS; i += 256) scnt[i] = 0;
  __syncthreads();
  for (int i = blockIdx.x * 256 + threadIdx.x; i < B; i += gridDim.x * 256)
    atomicAdd(&scnt[tgt[i]], 1);
  __syncthreads();
  for (int i = threadIdx.x; i < CCLS; i += 256) {
    int v = scnt[i];
    if (v) atomicAdd(&g_cnt[i], (float)v);
  }
}

// ---------------- epilogue: mean |avg_conf - avg_count| ----------------
__global__ __launch_bounds__(256) void mdca_final(const float* __restrict__ g_acc,
                                                  const float* __restrict__ g_cnt,
                                                  float* __restrict__ out, int B) {
  __shared__ float s_r[4];
  int t = threadIdx.x;
  float invB = 1.0f / (float)B;
  float s = 0.f;
  for (int c = t; c < CCLS; c += 256)
    s += fabsf((g_acc[c] - g_cnt[c]) * invB);
  #pragma unroll
  for (int off = 32; off > 0; off >>= 1) s += __shfl_down(s, off, 64);
  if ((t & 63) == 0) s_r[t >> 6] = s;
  __syncthreads();
  if (t == 0) out[0] = (s_r[0] + s_r[1] + s_r[2] + s_r[3]) / (float)CCLS;
}

extern "C" void kernel_launch(void* const* d_in, const int* in_sizes, int n_in,
                              void* d_out, int out_size, void* d_ws, size_t ws_size,
                              hipStream_t stream) {
  const float* X = (const float*)d_in[0];
  const int* tgt = (const int*)d_in[1];
  const int B = in_sizes[1];

  float* g_acc = (float*)d_ws;   // [1024] (first 1000 used)
  float* g_cnt = g_acc + 1024;   // [1024]

  hipMemsetAsync(d_ws, 0, 2048 * sizeof(float), stream);

  mdca_main<<<NBLK, TPB, 0, stream>>>(X, g_acc, B);
  mdca_count<<<32, 256, 0, stream>>>(tgt, g_cnt, B);
  mdca_final<<<1, 256, 0, stream>>>(g_acc, g_cnt, (float*)d_out, B);
}